// Round 1
// 1034.332 us; speedup vs baseline: 1.0278x; 1.0278x over previous
//
#include <hip/hip_runtime.h>
#include <cstddef>

// RecurrentFRAdamaxAttention fused kernel, v3.
// Shapes: N=1024, H=8, D=64, M=64. All fp32.
// One workgroup per (n,h). Changes vs v2:
//  - Pi/Mi prefetched into registers BEFORE the mu-reduction barriers, so
//    8 float4 loads/thread remain in flight across the reduction dead window.
//  - V = Z * (Q^T Si) accumulated in registers (each thread owns one fixed
//    float4 column t&15 across 4 d-rows); 2-step shfl + 1 KiB LDS combine.
//    Deletes the 16 KiB Sl staging, the vred buffer, and one barrier.
//  - value row read directly from global (16 unique float4/block, L1 hits);
//    no LDS staging for it.
//  - Non-temporal loads/stores on all five (D,M) input and output streams
//    (every byte touched exactly once; keep them out of L2/L3).
// HBM traffic ~1.355 GB -> memory-bound, roofline ~215 us @ 6.3 TB/s.

namespace {

constexpr float EPS      = 1e-6f;
constexpr float STEPSIZE = 0.5f;
constexpr float BETA     = 0.9f;
constexpr float DELTA    = 0.001f;

constexpr size_t NHD  = 1024ull * 8 * 64;        // 524288
constexpr size_t NHDM = 1024ull * 8 * 64 * 64;   // 33554432

// Output layout (concatenated flat, reference return order):
// (V, Si, Zi_new, Pi_new, Mi_new, Ui, Siprev)
constexpr size_t OFF_V  = 0;
constexpr size_t OFF_SI = OFF_V  + NHD;    // 524288
constexpr size_t OFF_ZN = OFF_SI + NHDM;   // 34078720
constexpr size_t OFF_PN = OFF_ZN + NHD;    // 34603008
constexpr size_t OFF_MN = OFF_PN + NHDM;   // 68157440
constexpr size_t OFF_UI = OFF_MN + NHDM;   // 101711872
constexpr size_t OFF_SP = OFF_UI + NHDM;   // 135266304

typedef float f4 __attribute__((ext_vector_type(4)));

__device__ __forceinline__ f4 ntload(const f4* p) {
    return __builtin_nontemporal_load(p);
}
__device__ __forceinline__ void ntstore(f4* p, f4 v) {
    __builtin_nontemporal_store(v, p);
}

__device__ __forceinline__ float featmap(float x) {
    // elu(x) + 1 == (x > 0 ? x + 1 : exp(x))
    return x > 0.0f ? x + 1.0f : __expf(x);
}

} // namespace

__global__ __launch_bounds__(256)
void fra_adamax_fused(const float* __restrict__ query,
                      const float* __restrict__ key,
                      const float* __restrict__ value,
                      const float* __restrict__ Siprev,
                      const float* __restrict__ Zi,
                      const float* __restrict__ Pi,
                      const float* __restrict__ Mi,
                      const float* __restrict__ Uiprev,
                      const float* __restrict__ Siprev2,
                      float* __restrict__ out)
{
    __shared__ float Qf[64];
    __shared__ float Kf[64];
    __shared__ float red[12];      // 4 wave partials x {du, ds, qz}
    __shared__ float bro[2];       // {mu, Z}
    __shared__ f4    vpart[64];    // 4 waves x 16 column-float4 V partials

    const int    t   = threadIdx.x;
    const int    nh  = blockIdx.x;
    const size_t vb  = (size_t)nh * 64;     // base into (N,H,D)-shaped arrays
    const size_t mb4 = (size_t)nh * 1024;   // base into (N,H,D,M), float4 units

    // This thread's fixed value-row column float4 (f4 column = t & 15 for all
    // four j iterations since 256 % 16 == 0). 16 unique float4 per block.
    const f4 vrow = *((const f4*)value + (size_t)nh * 16 + (t & 15));

    // ---- Phase A: feature maps + Zi_new ----------------------------------
    float qz = 0.0f;
    if (t < 64) {
        const float q  = featmap(query[vb + t]);
        const float k  = featmap(key[vb + t]);
        const float zn = Zi[vb + t] + k;
        Qf[t] = q;
        Kf[t] = k;
        out[OFF_ZN + vb + t] = zn;
        qz = q * zn;                        // partial of dot(Q, Zi_new)
    }
    __syncthreads();

    const f4* Sp4  = (const f4*)Siprev  + mb4;
    const f4* Up4  = (const f4*)Uiprev  + mb4;
    const f4* Sp24 = (const f4*)Siprev2 + mb4;
    const f4* Pi4  = (const f4*)Pi      + mb4;
    const f4* Mi4  = (const f4*)Mi      + mb4;
    f4* oUi = (f4*)(out + OFF_UI) + mb4;
    f4* oSp = (f4*)(out + OFF_SP) + mb4;
    f4* oSi = (f4*)(out + OFF_SI) + mb4;
    f4* oPn = (f4*)(out + OFF_PN) + mb4;
    f4* oMn = (f4*)(out + OFF_MN) + mb4;

    // ---- Phase B: Ui = K (x) value; norm partials; stream Ui & Siprev -----
    f4 ui[4], sp[4], pr[4], mr[4];
    float du = 0.0f, ds = 0.0f;
    #pragma unroll
    for (int j = 0; j < 4; ++j) {
        const int   f  = j * 256 + t;       // float4 index in [0,1024)
        const float kd = Kf[f >> 4];        // row d = f>>4 (16 f4 per row)
        const f4 up = ntload(Up4 + f);
        const f4 s  = ntload(Sp4 + f);
        const f4 s2 = ntload(Sp24 + f);

        const f4 u = kd * vrow;
        const f4 e = u - up;
        du += e.x * e.x + e.y * e.y + e.z * e.z + e.w * e.w;
        const f4 g = s - s2;
        ds += g.x * g.x + g.y * g.y + g.z * g.z + g.w * g.w;

        ui[j] = u;
        sp[j] = s;
        ntstore(oUi + f, u);    // output: Ui
        ntstore(oSp + f, s);    // output: Siprev (pass-through copy)
    }

    // Prefetch Pi/Mi NOW so these 8 loads are in flight across the
    // reduction + barriers below instead of starting cold after them.
    #pragma unroll
    for (int j = 0; j < 4; ++j) {
        const int f = j * 256 + t;
        pr[j] = ntload(Pi4 + f);
        mr[j] = ntload(Mi4 + f);
    }

    // ---- Phase C: block reduction -> mu, Z --------------------------------
    #pragma unroll
    for (int off = 32; off > 0; off >>= 1) {
        du += __shfl_down(du, off);
        ds += __shfl_down(ds, off);
        qz += __shfl_down(qz, off);
    }
    const int wave = t >> 6;
    if ((t & 63) == 0) {
        red[wave]     = du;
        red[4 + wave] = ds;
        red[8 + wave] = qz;
    }
    __syncthreads();
    if (t == 0) {
        const float DU = red[0] + red[1] + red[2]  + red[3];
        const float DS = red[4] + red[5] + red[6]  + red[7];
        const float QZ = red[8] + red[9] + red[10] + red[11];
        const float r  = sqrtf(STEPSIZE * sqrtf(DU) / sqrtf(DS));
        const float om = 1.0f - r;
        float mu = om * om;
        mu = fminf(mu, 1.0f - DELTA);
        mu = fmaxf(mu, 0.0f);
        bro[0] = mu;
        bro[1] = 1.0f / (QZ + EPS);
    }
    __syncthreads();
    const float mu = bro[0];
    const float Z  = bro[1];

    // ---- Phase D: Pi_new / Mi_new / Si; accumulate Q[d]*Si in registers ---
    f4 vacc = {0.0f, 0.0f, 0.0f, 0.0f};
    #pragma unroll
    for (int j = 0; j < 4; ++j) {
        const int   f  = j * 256 + t;
        const float qd = Qf[f >> 4];
        const f4 p = pr[j];
        const f4 m = mr[j];
        const f4 u = ui[j];
        const f4 s = sp[j];

        const f4 pn = mu * p - STEPSIZE * u;

        f4 mn;
        mn.x = fmaxf(BETA * m.x, fabsf(u.x));
        mn.y = fmaxf(BETA * m.y, fabsf(u.y));
        mn.z = fmaxf(BETA * m.z, fabsf(u.z));
        mn.w = fmaxf(BETA * m.w, fabsf(u.w));

        f4 si;
        si.x = s.x - pn.x * rsqrtf(mn.x + 1e-16f);
        si.y = s.y - pn.y * rsqrtf(mn.y + 1e-16f);
        si.z = s.z - pn.z * rsqrtf(mn.z + 1e-16f);
        si.w = s.w - pn.w * rsqrtf(mn.w + 1e-16f);

        ntstore(oPn + f, pn);
        ntstore(oMn + f, mn);
        ntstore(oSi + f, si);
        vacc += qd * si;
    }

    // ---- Phase E: V[m] = Z * sum_d Q[d]*Si[d][m], register reduction ------
    // Threads sharing t&15 hold the same columns, different d. Within a wave
    // those are lanes {c, c+16, c+32, c+48}: two shfl_down steps reduce them.
    #pragma unroll
    for (int off = 32; off >= 16; off >>= 1) {
        vacc.x += __shfl_down(vacc.x, off);
        vacc.y += __shfl_down(vacc.y, off);
        vacc.z += __shfl_down(vacc.z, off);
        vacc.w += __shfl_down(vacc.w, off);
    }
    if ((t & 63) < 16)
        vpart[wave * 16 + (t & 15)] = vacc;
    __syncthreads();
    if (t < 64) {
        const float* vp = (const float*)vpart;   // [wave][m] as 4 x 64 floats
        const float v = vp[t] + vp[64 + t] + vp[128 + t] + vp[192 + t];
        out[OFF_V + vb + t] = Z * v;
    }
}

extern "C" void kernel_launch(void* const* d_in, const int* in_sizes, int n_in,
                              void* d_out, int out_size, void* d_ws, size_t ws_size,
                              hipStream_t stream) {
    const float* query   = (const float*)d_in[0];
    const float* key     = (const float*)d_in[1];
    const float* value   = (const float*)d_in[2];
    const float* Siprev  = (const float*)d_in[3];
    const float* Zi      = (const float*)d_in[4];
    const float* Pi      = (const float*)d_in[5];
    const float* Mi      = (const float*)d_in[6];
    const float* Uiprev  = (const float*)d_in[7];
    const float* Siprev2 = (const float*)d_in[8];
    float* out = (float*)d_out;

    const int nh = in_sizes[0] / 64;  // N*H = 8192
    fra_adamax_fused<<<nh, 256, 0, stream>>>(query, key, value, Siprev, Zi,
                                             Pi, Mi, Uiprev, Siprev2, out);
}